// Round 4
// baseline (235.243 us; speedup 1.0000x reference)
//
#include <hip/hip_runtime.h>
#include <hip/hip_bf16.h>

// out[bh][m][d] = sum_k x1[bh][m][k] * x2[bh][k][d];  BH=32, S=2048, D=64, fp32.
// HBM-bound on x1 (537 MB). Structure (R3 = R2 with ext_vector fix):
//   kernel 1: x2 [bh][k][d] fp32 -> x2t [bh][d][k] bf16 in d_ws (8 MB, ~5 us)
//   kernel 2: barrier-free streaming GEMM. No LDS. B-fragments are contiguous
//     dwordx4 loads from x2t (L2-hot: 2 MB/XCD working set w/ XCD swizzle).
//     A: depth-1 register ping-pong prefetch; B issued before A(t+1) so the
//     counted vmcnt wait on B never drains the A prefetch (FIFO order).
//     Nontemporal on x1 (zero reuse) to keep x2t resident in L2.

#define S_DIM 2048
#define D_DIM 64
#define BM 128
#define BK 128
#define NT (S_DIM / BK)   // 16
#define LDB (BK + 8)

typedef __attribute__((ext_vector_type(8))) short short8;
typedef __attribute__((ext_vector_type(4))) short short4v;
typedef __attribute__((ext_vector_type(4))) float f32x4;

__device__ __forceinline__ short f2bf(float x) {
    return __builtin_bit_cast(short, __float2bfloat16(x));
}

// ---------------- kernel 1: transpose + bf16 convert of x2 ----------------
__global__ __launch_bounds__(256)
void x2_transpose_kernel(const float* __restrict__ x2, short* __restrict__ x2t) {
    __shared__ float tile[64][65];
    int bh = blockIdx.x >> 5;            // 32 k-blocks per bh
    int kb = (blockIdx.x & 31) * 64;
    int t  = threadIdx.x;
    int d  = t & 63;
    int k4 = t >> 6;                     // 0..3
    const float* src = x2 + ((size_t)bh * S_DIM + kb) * D_DIM + d;
#pragma unroll
    for (int i = 0; i < 16; ++i)
        tile[i * 4 + k4][d] = src[(size_t)(i * 4 + k4) * D_DIM];
    __syncthreads();
    int dcol = t >> 2;                   // 0..63
    int kg   = (t & 3) * 16;             // 0,16,32,48
    short8 v0, v1;
#pragma unroll
    for (int j = 0; j < 8; ++j) {
        v0[j] = f2bf(tile[kg + j][dcol]);
        v1[j] = f2bf(tile[kg + 8 + j][dcol]);
    }
    short* dst = x2t + ((size_t)bh * D_DIM + dcol) * S_DIM + kb + kg;
    *(short8*)dst = v0;
    *(short8*)(dst + 8) = v1;
}

// ---------------- kernel 2: barrier-free streaming GEMM ----------------
__global__ __launch_bounds__(512, 2)
void pv_gemm_l2b_kernel(const float* __restrict__ x1,
                        const short* __restrict__ x2t,
                        float* __restrict__ out) {
    // XCD-aware bijective swizzle (512 % 8 == 0): XCD gets 4 bh (2 MB x2t in L2)
    int bid = blockIdx.x;
    int lb  = (bid & 7) * 64 + (bid >> 3);
    int bh   = lb >> 4;
    int mblk = lb & 15;
    int m0   = mblk * BM;

    int tid  = threadIdx.x;
    int lane = tid & 63;
    int w    = tid >> 6;

    // A fragment (mfma 16x16x32 bf16): row = lane&15, k = (lane>>4)*8 + j
    int arow = m0 + w * 16 + (lane & 15);
    int kgrp = (lane >> 4) * 8;
    const float* aptr = x1 + ((size_t)bh * S_DIM + arow) * S_DIM + kgrp;

    // B fragment: n = lane&15 (+ni*16), k contiguous in x2t[bh][d][k]
    const short* bbase = x2t + ((size_t)bh * D_DIM + (lane & 15)) * S_DIM + kgrp;
    const short* bp_ni0 = bbase;
    const short* bp_ni1 = bbase + (size_t)16 * S_DIM;
    const short* bp_ni2 = bbase + (size_t)32 * S_DIM;
    const short* bp_ni3 = bbase + (size_t)48 * S_DIM;

    f32x4 acc[4];
#pragma unroll
    for (int i = 0; i < 4; ++i) acc[i] = (f32x4){0.f, 0.f, 0.f, 0.f};

    // prologue: A tile 0
    f32x4 rA0[8], rA1[8];
#pragma unroll
    for (int kk = 0; kk < 4; ++kk) {
        rA0[2 * kk]     = __builtin_nontemporal_load((const f32x4*)(aptr + kk * 32));
        rA0[2 * kk + 1] = __builtin_nontemporal_load((const f32x4*)(aptr + kk * 32 + 4));
    }

// One K-step: B(t) loads first (older in vmcnt FIFO), A(t+1) second (stays in
// flight across the step), then compute. No barriers anywhere.
#define ITER(T, RA_CUR, RA_NXT)                                               \
    {                                                                         \
        const short* b0 = bp_ni0 + (size_t)(T) * BK;                          \
        const short* b1 = bp_ni1 + (size_t)(T) * BK;                          \
        const short* b2 = bp_ni2 + (size_t)(T) * BK;                          \
        const short* b3 = bp_ni3 + (size_t)(T) * BK;                          \
        short8 vb[16];                                                        \
        _Pragma("unroll")                                                     \
        for (int kk = 0; kk < 4; ++kk) {                                      \
            vb[kk * 4 + 0] = *(const short8*)(b0 + kk * 32);                  \
            vb[kk * 4 + 1] = *(const short8*)(b1 + kk * 32);                  \
            vb[kk * 4 + 2] = *(const short8*)(b2 + kk * 32);                  \
            vb[kk * 4 + 3] = *(const short8*)(b3 + kk * 32);                  \
        }                                                                     \
        if ((T) + 1 < NT) {                                                   \
            const float* an = aptr + (size_t)((T) + 1) * BK;                  \
            _Pragma("unroll")                                                 \
            for (int kk = 0; kk < 4; ++kk) {                                  \
                RA_NXT[2 * kk] = __builtin_nontemporal_load(                  \
                    (const f32x4*)(an + kk * 32));                            \
                RA_NXT[2 * kk + 1] = __builtin_nontemporal_load(              \
                    (const f32x4*)(an + kk * 32 + 4));                        \
            }                                                                 \
        }                                                                     \
        _Pragma("unroll")                                                     \
        for (int kk = 0; kk < 4; ++kk) {                                      \
            short8 a;                                                         \
            a[0] = f2bf(RA_CUR[2 * kk][0]);                                   \
            a[1] = f2bf(RA_CUR[2 * kk][1]);                                   \
            a[2] = f2bf(RA_CUR[2 * kk][2]);                                   \
            a[3] = f2bf(RA_CUR[2 * kk][3]);                                   \
            a[4] = f2bf(RA_CUR[2 * kk + 1][0]);                               \
            a[5] = f2bf(RA_CUR[2 * kk + 1][1]);                               \
            a[6] = f2bf(RA_CUR[2 * kk + 1][2]);                               \
            a[7] = f2bf(RA_CUR[2 * kk + 1][3]);                               \
            acc[0] = __builtin_amdgcn_mfma_f32_16x16x32_bf16(                 \
                a, vb[kk * 4 + 0], acc[0], 0, 0, 0);                          \
            acc[1] = __builtin_amdgcn_mfma_f32_16x16x32_bf16(                 \
                a, vb[kk * 4 + 1], acc[1], 0, 0, 0);                          \
            acc[2] = __builtin_amdgcn_mfma_f32_16x16x32_bf16(                 \
                a, vb[kk * 4 + 2], acc[2], 0, 0, 0);                          \
            acc[3] = __builtin_amdgcn_mfma_f32_16x16x32_bf16(                 \
                a, vb[kk * 4 + 3], acc[3], 0, 0, 0);                          \
        }                                                                     \
    }

    for (int t = 0; t < NT; t += 2) {
        ITER(t,     rA0, rA1);
        ITER(t + 1, rA1, rA0);
    }
#undef ITER

    // epilogue: C/D layout col = lane&15, row = (lane>>4)*4 + reg
    int col0 = lane & 15;
    int r0   = m0 + w * 16 + ((lane >> 4) << 2);
    float* ob = out + ((size_t)bh * S_DIM + r0) * D_DIM + col0;
#pragma unroll
    for (int ni = 0; ni < 4; ++ni) {
#pragma unroll
        for (int r = 0; r < 4; ++r)
            ob[(size_t)r * D_DIM + ni * 16] = acc[ni][r];
    }
}

// ---------------- fallback (R1 kernel): used only if ws too small ----------
__global__ __launch_bounds__(512, 4)
void pv_gemm_lds_kernel(const float* __restrict__ x1,
                        const float* __restrict__ x2,
                        float* __restrict__ out) {
    __shared__ short lds_b[2][D_DIM][LDB];
    int bid = blockIdx.x;
    int lb  = (bid & 7) * 64 + (bid >> 3);
    int bh   = lb >> 4;
    int mblk = lb & 15;
    int m0   = mblk * BM;
    int tid  = threadIdx.x;
    int lane = tid & 63;
    int w    = tid >> 6;
    int sd  = tid & 63;
    int skb = tid >> 6;
    const float* x2base = x2 + (size_t)bh * S_DIM * D_DIM + sd;
    int arow = m0 + w * 16 + (lane & 15);
    int kgrp = (lane >> 4) * 8;
    const float* abase = x1 + ((size_t)bh * S_DIM + arow) * S_DIM + kgrp;
    f32x4 acc[4];
#pragma unroll
    for (int i = 0; i < 4; ++i) acc[i] = (f32x4){0.f, 0.f, 0.f, 0.f};
    {
        float rs[16];
#pragma unroll
        for (int i = 0; i < 16; ++i)
            rs[i] = x2base[(size_t)(skb * 16 + i) * D_DIM];
#pragma unroll
        for (int j = 0; j < 4; ++j) {
            short4v v;
            v[0] = f2bf(rs[4 * j + 0]); v[1] = f2bf(rs[4 * j + 1]);
            v[2] = f2bf(rs[4 * j + 2]); v[3] = f2bf(rs[4 * j + 3]);
            *(short4v*)&lds_b[0][sd][skb * 16 + 4 * j] = v;
        }
    }
    int buf = 0;
    for (int t = 0; t < NT; ++t) {
        __syncthreads();
        float rn[16];
        if (t + 1 < NT) {
            const float* p = x2base + (size_t)(t + 1) * BK * D_DIM;
#pragma unroll
            for (int i = 0; i < 16; ++i)
                rn[i] = p[(size_t)(skb * 16 + i) * D_DIM];
        }
        const float* ab = abase + (size_t)t * BK;
#pragma unroll
        for (int kk = 0; kk < 4; ++kk) {
            float4 lo = *(const float4*)(ab + kk * 32);
            float4 hi = *(const float4*)(ab + kk * 32 + 4);
            short8 a;
            a[0] = f2bf(lo.x); a[1] = f2bf(lo.y); a[2] = f2bf(lo.z); a[3] = f2bf(lo.w);
            a[4] = f2bf(hi.x); a[5] = f2bf(hi.y); a[6] = f2bf(hi.z); a[7] = f2bf(hi.w);
#pragma unroll
            for (int ni = 0; ni < 4; ++ni) {
                const short8* bp =
                    (const short8*)&lds_b[buf][ni * 16 + (lane & 15)][kk * 32 + kgrp];
                acc[ni] = __builtin_amdgcn_mfma_f32_16x16x32_bf16(a, *bp, acc[ni], 0, 0, 0);
            }
        }
        if (t + 1 < NT) {
#pragma unroll
            for (int j = 0; j < 4; ++j) {
                short4v v;
                v[0] = f2bf(rn[4 * j + 0]); v[1] = f2bf(rn[4 * j + 1]);
                v[2] = f2bf(rn[4 * j + 2]); v[3] = f2bf(rn[4 * j + 3]);
                *(short4v*)&lds_b[buf ^ 1][sd][skb * 16 + 4 * j] = v;
            }
        }
        buf ^= 1;
    }
    int col0 = lane & 15;
    int r0   = m0 + w * 16 + ((lane >> 4) << 2);
    float* ob = out + ((size_t)bh * S_DIM + r0) * D_DIM + col0;
#pragma unroll
    for (int ni = 0; ni < 4; ++ni) {
#pragma unroll
        for (int r = 0; r < 4; ++r)
            ob[(size_t)r * D_DIM + ni * 16] = acc[ni][r];
    }
}

extern "C" void kernel_launch(void* const* d_in, const int* in_sizes, int n_in,
                              void* d_out, int out_size, void* d_ws, size_t ws_size,
                              hipStream_t stream) {
    const float* x1 = (const float*)d_in[0];   // [2,16,2048,2048]
    const float* x2 = (const float*)d_in[1];   // [2,16,2048,64]
    float* out = (float*)d_out;                // [2,16,2048,64]

    const size_t need = (size_t)32 * D_DIM * S_DIM * sizeof(short);  // 8 MB
    if (ws_size >= need) {
        short* x2t = (short*)d_ws;
        hipLaunchKernelGGL(x2_transpose_kernel, dim3(1024), dim3(256), 0, stream,
                           x2, x2t);
        hipLaunchKernelGGL(pv_gemm_l2b_kernel, dim3(512), dim3(512), 0, stream,
                           x1, x2t, out);
    } else {
        hipLaunchKernelGGL(pv_gemm_lds_kernel, dim3(512), dim3(512), 0, stream,
                           x1, x2, out);
    }
}

// Round 5
// 154.248 us; speedup vs baseline: 1.5251x; 1.5251x over previous
//
#include <hip/hip_runtime.h>
#include <hip/hip_bf16.h>

// out[bh][m][d] = sum_k x1[bh][m][k] * x2[bh][k][d];  BH=32, S=2048(M,K), D=64(N), fp32.
// HBM-bound on x1 (537 MB, zero reuse). bf16 MFMA 16x16x32, fp32 acc.
// R5 = R2 (LDS-staged x2, double-buffered, reg ping-pong A prefetch) with the
// __syncthreads() replaced by a NO-DRAIN barrier:
//     s_waitcnt lgkmcnt(0); s_barrier        (vmcnt NOT drained)
// so the A-prefetch (pure VMEM) stays in flight across all 16 K-step barriers.
// x2-next loads issue BEFORE A-next loads (older in vmcnt FIFO): the ds_write's
// implicit vmcnt wait on x2 never drains A. x1 loads are nontemporal (no reuse)
// to keep x2 L2-resident for the 16 M-blocks per bh.

#define S_DIM 2048
#define D_DIM 64
#define BM 128
#define BK 128
#define NT (S_DIM / BK)   // 16 K-steps
#define LDB (BK + 8)      // byte stride 272: 16B-aligned, 2-way bank pattern (free)

typedef __attribute__((ext_vector_type(8))) short short8;
typedef __attribute__((ext_vector_type(4))) short short4v;
typedef __attribute__((ext_vector_type(4))) float f32x4;

__device__ __forceinline__ short f2bf(float x) {
    return __builtin_bit_cast(short, __float2bfloat16(x));
}

// Workgroup barrier that waits ONLY on LDS ops (lgkmcnt), leaving global
// loads (vmcnt) in flight. sched_barrier(0) on both sides pins the compiler
// so no LDS op migrates across (rule #18 / m152 discipline).
__device__ __forceinline__ void barrier_keep_vmem_inflight() {
    __builtin_amdgcn_sched_barrier(0);
    asm volatile("s_waitcnt lgkmcnt(0)" ::: "memory");
    __builtin_amdgcn_s_barrier();
    __builtin_amdgcn_sched_barrier(0);
}

__global__ __launch_bounds__(512, 4)
void pv_gemm_kernel(const float* __restrict__ x1,
                    const float* __restrict__ x2,
                    float* __restrict__ out) {
    __shared__ short lds_b[2][D_DIM][LDB];   // 34,816 bytes -> 2 blocks/CU

    // XCD-aware bijective swizzle (512 % 8 == 0): 4 bh per XCD -> x2 slice
    // (4 x 512 KB fp32) L2-resident per XCD.
    int bid = blockIdx.x;
    int lb  = (bid & 7) * 64 + (bid >> 3);
    int bh   = lb >> 4;
    int mblk = lb & 15;
    int m0   = mblk * BM;

    int tid  = threadIdx.x;
    int lane = tid & 63;
    int w    = tid >> 6;

    // x2 staging coords: thread t loads column d = t&63, k-block t>>6 (16 k's)
    int sd  = tid & 63;
    int skb = tid >> 6;
    const float* x2base = x2 + (size_t)bh * S_DIM * D_DIM + sd;

    // A fragment coords (mfma 16x16x32 bf16: row = lane&15, k = (lane>>4)*8 + j)
    int arow = m0 + w * 16 + (lane & 15);
    int kgrp = (lane >> 4) * 8;
    const float* abase = x1 + ((size_t)bh * S_DIM + arow) * S_DIM + kgrp;

    f32x4 acc[4];
#pragma unroll
    for (int i = 0; i < 4; ++i) acc[i] = (f32x4){0.f, 0.f, 0.f, 0.f};

    // ---- prologue: stage x2 tile 0 into LDS buffer 0
    {
        float rs[16];
#pragma unroll
        for (int i = 0; i < 16; ++i)
            rs[i] = x2base[(size_t)(skb * 16 + i) * D_DIM];
#pragma unroll
        for (int j = 0; j < 4; ++j) {
            short4v v;
            v[0] = f2bf(rs[4 * j + 0]);
            v[1] = f2bf(rs[4 * j + 1]);
            v[2] = f2bf(rs[4 * j + 2]);
            v[3] = f2bf(rs[4 * j + 3]);
            *(short4v*)&lds_b[0][sd][skb * 16 + 4 * j] = v;
        }
    }

    // ---- prologue: load A tile 0 into rA0 (nontemporal: x1 has zero reuse)
    f32x4 rA0[8], rA1[8];
#pragma unroll
    for (int kk = 0; kk < 4; ++kk) {
        rA0[2 * kk]     = __builtin_nontemporal_load((const f32x4*)(abase + kk * 32));
        rA0[2 * kk + 1] = __builtin_nontemporal_load((const f32x4*)(abase + kk * 32 + 4));
    }

// One K-step. RBUF: static LDS read-buffer index. RA_CUR: A regs for this
// step (already loaded). RA_NXT: filled for next step. x2 loads issue FIRST
// (older in vmcnt FIFO), so the ds_write's wait on them leaves A in flight.
#define ITER(T, RBUF, RA_CUR, RA_NXT)                                        \
    {                                                                        \
        barrier_keep_vmem_inflight();                                        \
        float rn[16];                                                        \
        if ((T) + 1 < NT) {                                                  \
            const float* p = x2base + (size_t)((T) + 1) * BK * D_DIM;        \
            _Pragma("unroll")                                                \
            for (int i = 0; i < 16; ++i)                                     \
                rn[i] = p[(size_t)(skb * 16 + i) * D_DIM];                   \
            const float* an = abase + (size_t)((T) + 1) * BK;                \
            _Pragma("unroll")                                                \
            for (int kk = 0; kk < 4; ++kk) {                                 \
                RA_NXT[2 * kk] = __builtin_nontemporal_load(                 \
                    (const f32x4*)(an + kk * 32));                           \
                RA_NXT[2 * kk + 1] = __builtin_nontemporal_load(             \
                    (const f32x4*)(an + kk * 32 + 4));                       \
            }                                                                \
        }                                                                    \
        _Pragma("unroll")                                                    \
        for (int kk = 0; kk < 4; ++kk) {                                     \
            short8 a;                                                        \
            a[0] = f2bf(RA_CUR[2 * kk][0]);                                  \
            a[1] = f2bf(RA_CUR[2 * kk][1]);                                  \
            a[2] = f2bf(RA_CUR[2 * kk][2]);                                  \
            a[3] = f2bf(RA_CUR[2 * kk][3]);                                  \
            a[4] = f2bf(RA_CUR[2 * kk + 1][0]);                              \
            a[5] = f2bf(RA_CUR[2 * kk + 1][1]);                              \
            a[6] = f2bf(RA_CUR[2 * kk + 1][2]);                              \
            a[7] = f2bf(RA_CUR[2 * kk + 1][3]);                              \
            _Pragma("unroll")                                                \
            for (int ni = 0; ni < 4; ++ni) {                                 \
                const short8* bp = (const short8*)                           \
                    &lds_b[RBUF][ni * 16 + (lane & 15)][kk * 32 + kgrp];     \
                acc[ni] = __builtin_amdgcn_mfma_f32_16x16x32_bf16(           \
                    a, *bp, acc[ni], 0, 0, 0);                               \
            }                                                                \
        }                                                                    \
        if ((T) + 1 < NT) {                                                  \
            _Pragma("unroll")                                                \
            for (int j = 0; j < 4; ++j) {                                    \
                short4v v;                                                   \
                v[0] = f2bf(rn[4 * j + 0]);                                  \
                v[1] = f2bf(rn[4 * j + 1]);                                  \
                v[2] = f2bf(rn[4 * j + 2]);                                  \
                v[3] = f2bf(rn[4 * j + 3]);                                  \
                *(short4v*)&lds_b[(RBUF) ^ 1][sd][skb * 16 + 4 * j] = v;     \
            }                                                                \
        }                                                                    \
    }

    for (int t = 0; t < NT; t += 2) {
        ITER(t,     0, rA0, rA1);
        ITER(t + 1, 1, rA1, rA0);
    }
#undef ITER

    // ---- epilogue: C/D layout col = lane&15, row = (lane>>4)*4 + reg
    int col0 = lane & 15;
    int r0   = m0 + w * 16 + ((lane >> 4) << 2);
    float* ob = out + ((size_t)bh * S_DIM + r0) * D_DIM + col0;
#pragma unroll
    for (int ni = 0; ni < 4; ++ni) {
#pragma unroll
        for (int r = 0; r < 4; ++r)
            ob[(size_t)r * D_DIM + ni * 16] = acc[ni][r];
    }
}

extern "C" void kernel_launch(void* const* d_in, const int* in_sizes, int n_in,
                              void* d_out, int out_size, void* d_ws, size_t ws_size,
                              hipStream_t stream) {
    const float* x1 = (const float*)d_in[0];   // [2,16,2048,2048] softmax probs
    const float* x2 = (const float*)d_in[1];   // [2,16,2048,64]
    float* out = (float*)d_out;                // [2,16,2048,64]

    dim3 grid(512);   // 32 bh * 16 M-tiles
    dim3 block(512);  // 8 waves
    hipLaunchKernelGGL(pv_gemm_kernel, grid, block, 0, stream, x1, x2, out);
}

// Round 6
// 137.095 us; speedup vs baseline: 1.7159x; 1.1251x over previous
//
#include <hip/hip_runtime.h>
#include <hip/hip_bf16.h>

// out[bh][m][d] = sum_k x1[bh][m][k] * x2[bh][k][d];  BH=32, S=2048(M,K), D=64(N), fp32.
// HBM-bound on x1 (537 MB, zero reuse). bf16 MFMA 16x16x32, fp32 acc.
//
// R6 design (split-K, barrier-free main loop, k-rotation):
//  - Split K into 2 halves of 1024. Grid = 32 bh x 8 mblk(BM=256) x 2 kh = 512 blocks.
//  - Per block: stage its x2 K-half ONCE into LDS [64 d][1024 k] bf16 (128 KB),
//    16B-granule XOR swizzle (ko ^= d&7) -> conflict-free ds_write_b128/ds_read_b128.
//    ONE __syncthreads after staging; main K-loop has NO barriers at all.
//  - Each wave processes the 8 K-steps (BK=128) in rotated order phase=(w+mblk)&7:
//    the block's 8 waves read 8 different 512B k-columns at any instant ->
//    spreads the 8KB-stride (power-of-2) x1 row accesses across HBM channels.
//  - Depth-1 register ping-pong A prefetch (R2's win, kept). No sched_barrier,
//    no nontemporal (R5's regression lessons).
//  - Epilogue: out zeroed via hipMemsetAsync, each kh-half atomicAdd's its
//    partial (exactly 2 commutative fp32 adds/element -> deterministic).

#define S_DIM 2048
#define D_DIM 64
#define BM    256
#define KH    1024
#define BK    128
#define NSTEP (KH / BK)   // 8

typedef __attribute__((ext_vector_type(8))) short short8;
typedef __attribute__((ext_vector_type(4))) float f32x4;

__device__ __forceinline__ short f2bf(float x) {
    return __builtin_bit_cast(short, __float2bfloat16(x));
}

__global__ __launch_bounds__(512, 2)
void pv_gemm_splitk(const float* __restrict__ x1,
                    const float* __restrict__ x2,
                    float* __restrict__ out) {
    // [d][ko] bf16, ko = k/8 (16B units), stored at byte d*2048 + ((ko^(d&7))<<4)
    __shared__ short ldsB[D_DIM * KH];   // 131072 B

    // XCD-aware bijective swizzle (512 % 8 == 0): 64 consecutive logical blocks
    // per XCD = 4 bh -> x2 slices L2-resident per XCD.
    int bid = blockIdx.x;
    int lb  = (bid & 7) * 64 + (bid >> 3);
    int bh   = lb >> 4;          // 0..31
    int mblk = (lb >> 1) & 7;    // 0..7
    int kh   = lb & 1;           // 0..1
    int m0   = mblk * BM;
    int k0   = kh * KH;

    int tid  = threadIdx.x;
    int lane = tid & 63;
    int w    = tid >> 6;         // wave 0..7

    int ll = lane & 15;          // fragment col / A-row-in-16
    int lh = lane >> 4;          // 0..3
    int xr = lane & 7;           // = d&7 for all d = ni*16+ll

    // A: row = m0 + mr*128 + w*16 + ll ; k = k0 + kstep*128 + kk*32 + lh*8 + j
    const float* aw = x1 + ((size_t)bh * S_DIM + m0 + w * 16 + ll) * S_DIM + k0 + lh * 8;

    int phase = (w + mblk + (kh << 2)) & 7;   // per-wave K-step rotation

    // ---- prologue: issue A loads for s=0 (kstep = phase) BEFORE staging,
    //      so their HBM latency hides under the staging phase.
    f32x4 rA0[16], rA1[16];
    {
        const float* an = aw + (size_t)phase * BK;
#pragma unroll
        for (int mr = 0; mr < 2; ++mr) {
            const float* am = an + (size_t)mr * 128 * S_DIM;
#pragma unroll
            for (int kk = 0; kk < 4; ++kk) {
                rA0[mr * 8 + 2 * kk]     = *(const f32x4*)(am + kk * 32);
                rA0[mr * 8 + 2 * kk + 1] = *(const f32x4*)(am + kk * 32 + 4);
            }
        }
    }

    // ---- stage x2[bh][k0 : k0+1024][*] -> ldsB (bf16, swizzled), once.
    {
        const float* xb = x2 + ((size_t)bh * S_DIM + k0) * D_DIM + lane;  // d = lane
        char* lrow = (char*)ldsB + (size_t)lane * (KH * 2);
        int dxr = lane & 7;
#pragma unroll
        for (int it = 0; it < 16; ++it) {
            int ko = w * 16 + it;                       // k-octet 0..127
            const float* p = xb + (size_t)ko * 8 * D_DIM;
            short8 v;
#pragma unroll
            for (int i = 0; i < 8; ++i)                 // wave reads 256B rows: coalesced
                v[i] = f2bf(p[(size_t)i * D_DIM]);
            *(short8*)(lrow + ((ko ^ dxr) << 4)) = v;   // conflict-free (XOR swizzle)
        }
    }
    __syncthreads();   // the ONLY block-wide barrier

    f32x4 acc[8];      // [mr*4 + ni]
#pragma unroll
    for (int i = 0; i < 8; ++i) acc[i] = (f32x4){0.f, 0.f, 0.f, 0.f};

    char* b0r = (char*)ldsB + (size_t)(0 * 16 + ll) * (KH * 2);
    char* b1r = (char*)ldsB + (size_t)(1 * 16 + ll) * (KH * 2);
    char* b2r = (char*)ldsB + (size_t)(2 * 16 + ll) * (KH * 2);
    char* b3r = (char*)ldsB + (size_t)(3 * 16 + ll) * (KH * 2);

// One K-step (no barriers): prefetch A for s+1 (rotated), then 32 MFMA on
// current regs + LDS-resident B. Compiler schedules freely.
#define STEP(S, RA_CUR, RA_NXT)                                               \
    {                                                                         \
        if ((S) + 1 < NSTEP) {                                                \
            int kn = ((S) + 1 + phase) & 7;                                   \
            const float* an = aw + (size_t)kn * BK;                           \
            _Pragma("unroll")                                                 \
            for (int mr = 0; mr < 2; ++mr) {                                  \
                const float* am = an + (size_t)mr * 128 * S_DIM;              \
                _Pragma("unroll")                                             \
                for (int kk = 0; kk < 4; ++kk) {                              \
                    RA_NXT[mr * 8 + 2 * kk]     = *(const f32x4*)(am + kk * 32);      \
                    RA_NXT[mr * 8 + 2 * kk + 1] = *(const f32x4*)(am + kk * 32 + 4);  \
                }                                                             \
            }                                                                 \
        }                                                                     \
        int kob = (((S) + phase) & 7) * 16;                                   \
        _Pragma("unroll")                                                     \
        for (int kk = 0; kk < 4; ++kk) {                                      \
            int koq = ((kob + kk * 4 + lh) ^ xr) << 4;                        \
            short8 vb0 = *(const short8*)(b0r + koq);                         \
            short8 vb1 = *(const short8*)(b1r + koq);                         \
            short8 vb2 = *(const short8*)(b2r + koq);                         \
            short8 vb3 = *(const short8*)(b3r + koq);                         \
            _Pragma("unroll")                                                 \
            for (int mr = 0; mr < 2; ++mr) {                                  \
                short8 a;                                                     \
                a[0] = f2bf(RA_CUR[mr * 8 + 2 * kk][0]);                      \
                a[1] = f2bf(RA_CUR[mr * 8 + 2 * kk][1]);                      \
                a[2] = f2bf(RA_CUR[mr * 8 + 2 * kk][2]);                      \
                a[3] = f2bf(RA_CUR[mr * 8 + 2 * kk][3]);                      \
                a[4] = f2bf(RA_CUR[mr * 8 + 2 * kk + 1][0]);                  \
                a[5] = f2bf(RA_CUR[mr * 8 + 2 * kk + 1][1]);                  \
                a[6] = f2bf(RA_CUR[mr * 8 + 2 * kk + 1][2]);                  \
                a[7] = f2bf(RA_CUR[mr * 8 + 2 * kk + 1][3]);                  \
                acc[mr * 4 + 0] = __builtin_amdgcn_mfma_f32_16x16x32_bf16(    \
                    a, vb0, acc[mr * 4 + 0], 0, 0, 0);                        \
                acc[mr * 4 + 1] = __builtin_amdgcn_mfma_f32_16x16x32_bf16(    \
                    a, vb1, acc[mr * 4 + 1], 0, 0, 0);                        \
                acc[mr * 4 + 2] = __builtin_amdgcn_mfma_f32_16x16x32_bf16(    \
                    a, vb2, acc[mr * 4 + 2], 0, 0, 0);                        \
                acc[mr * 4 + 3] = __builtin_amdgcn_mfma_f32_16x16x32_bf16(    \
                    a, vb3, acc[mr * 4 + 3], 0, 0, 0);                        \
            }                                                                 \
        }                                                                     \
    }

    for (int s = 0; s < NSTEP; s += 2) {
        STEP(s,     rA0, rA1);
        STEP(s + 1, rA1, rA0);
    }
#undef STEP

    // ---- epilogue: atomic accumulate (C/D: col = ll, row = lh*4 + r)
    int r0 = m0 + w * 16 + lh * 4;
#pragma unroll
    for (int mr = 0; mr < 2; ++mr) {
#pragma unroll
        for (int ni = 0; ni < 4; ++ni) {
#pragma unroll
            for (int r = 0; r < 4; ++r) {
                float* p = out + ((size_t)bh * S_DIM + r0 + mr * 128 + r) * D_DIM
                             + ni * 16 + ll;
                __hip_atomic_fetch_add(p, acc[mr * 4 + ni][r],
                                       __ATOMIC_RELAXED, __HIP_MEMORY_SCOPE_AGENT);
            }
        }
    }
}

extern "C" void kernel_launch(void* const* d_in, const int* in_sizes, int n_in,
                              void* d_out, int out_size, void* d_ws, size_t ws_size,
                              hipStream_t stream) {
    const float* x1 = (const float*)d_in[0];   // [2,16,2048,2048] softmax probs
    const float* x2 = (const float*)d_in[1];   // [2,16,2048,64]
    float* out = (float*)d_out;                // [2,16,2048,64]

    hipMemsetAsync(d_out, 0, (size_t)out_size * sizeof(float), stream);
    hipLaunchKernelGGL(pv_gemm_splitk, dim3(512), dim3(512), 0, stream,
                       x1, x2, out);
}

// Round 7
// 125.689 us; speedup vs baseline: 1.8716x; 1.0907x over previous
//
#include <hip/hip_runtime.h>
#include <hip/hip_bf16.h>

// out[bh][m][d] = sum_k x1[bh][m][k] * x2[bh][k][d];  BH=32, S=2048(M,K), D=64(N), fp32.
// HBM-bound on x1 (537 MB, zero reuse). bf16 MFMA 16x16x32, fp32 acc.
//
// R7 = R2's structure (LDS double-buffered x2, per-step __syncthreads, register
// ping-pong A prefetch, x2-loads-before-A-loads) resharded for finer barrier
// granularity: 256-thread blocks (BM=64), BK=64, grid=1024 -> 4 independent
// barrier domains per CU (vs R2's 2), same 16 waves/CU. When one block convoys
// at its barrier, 3 other blocks keep the CU's memory pipe busy.

#define S_DIM 2048
#define D_DIM 64
#define BM    64
#define BK    64
#define NT    (S_DIM / BK)   // 32 K-steps
#define LDB   (BK + 8)       // 72 shorts = 144 B row stride (16B-aligned)

typedef __attribute__((ext_vector_type(8))) short short8;
typedef __attribute__((ext_vector_type(4))) float f32x4;

__device__ __forceinline__ short f2bf(float x) {
    return __builtin_bit_cast(short, __float2bfloat16(x));
}

__global__ __launch_bounds__(256, 4)
void pv_gemm_kernel(const float* __restrict__ x1,
                    const float* __restrict__ x2,
                    float* __restrict__ out) {
    __shared__ short lds_b[2][D_DIM][LDB];   // 18,432 B -> 4 blocks/CU

    // XCD-aware bijective swizzle (1024 % 8 == 0): 128 consecutive logical
    // blocks per XCD = 4 bh -> that XCD's x2 slices (2 MB) stay L2-resident.
    int bid = blockIdx.x;
    int lb  = (bid & 7) * 128 + (bid >> 3);
    int bh   = lb >> 5;          // 0..31
    int mblk = lb & 31;          // 0..31
    int m0   = mblk * BM;

    int tid  = threadIdx.x;
    int lane = tid & 63;
    int w    = tid >> 6;         // wave 0..3

    int ll = lane & 15;
    int lh = lane >> 4;          // 0..3

    // x2 staging coords: thread t loads column d = t&63, k-row group t>>6
    int sd  = tid & 63;
    int skb = tid >> 6;          // 0..3 -> rows skb*16 .. skb*16+15
    const float* x2base = x2 + (size_t)bh * S_DIM * D_DIM + sd;

    // A fragment (mfma 16x16x32 bf16): row = lane&15, k = kk*32 + lh*8 + j
    const float* abase = x1 + ((size_t)bh * S_DIM + m0 + w * 16 + ll) * S_DIM + lh * 8;

    f32x4 acc[4];
#pragma unroll
    for (int i = 0; i < 4; ++i) acc[i] = (f32x4){0.f, 0.f, 0.f, 0.f};

    // ---- prologue: stage x2 K-tile 0 into LDS buffer 0
    {
        float rs[16];
#pragma unroll
        for (int i = 0; i < 16; ++i)
            rs[i] = x2base[(size_t)(skb * 16 + i) * D_DIM];
#pragma unroll
        for (int j = 0; j < 2; ++j) {
            short8 v;
#pragma unroll
            for (int e = 0; e < 8; ++e) v[e] = f2bf(rs[8 * j + e]);
            *(short8*)&lds_b[0][sd][skb * 16 + 8 * j] = v;
        }
    }

    // ---- prologue: load A tile 0 (4 x f32x4 = 16 floats per lane)
    f32x4 rA0[4], rA1[4];
#pragma unroll
    for (int kk = 0; kk < 2; ++kk) {
        rA0[2 * kk]     = *(const f32x4*)(abase + kk * 32);
        rA0[2 * kk + 1] = *(const f32x4*)(abase + kk * 32 + 4);
    }

// One K-step. x2(t+1) loads issue FIRST (older in vmcnt FIFO), A(t+1) second
// (stays in flight across the ds_write's implicit wait). Then 8 MFMA on the
// current regs + LDS B, then convert+ds_write the staged x2. Compiler-scheduled.
#define ITER(T, RBUF, RA_CUR, RA_NXT)                                        \
    {                                                                        \
        __syncthreads();                                                     \
        float rn[16];                                                        \
        if ((T) + 1 < NT) {                                                  \
            const float* p = x2base + (size_t)((T) + 1) * BK * D_DIM;        \
            _Pragma("unroll")                                                \
            for (int i = 0; i < 16; ++i)                                     \
                rn[i] = p[(size_t)(skb * 16 + i) * D_DIM];                   \
            const float* an = abase + (size_t)((T) + 1) * BK;                \
            _Pragma("unroll")                                                \
            for (int kk = 0; kk < 2; ++kk) {                                 \
                RA_NXT[2 * kk]     = *(const f32x4*)(an + kk * 32);          \
                RA_NXT[2 * kk + 1] = *(const f32x4*)(an + kk * 32 + 4);      \
            }                                                                \
        }                                                                    \
        _Pragma("unroll")                                                    \
        for (int kk = 0; kk < 2; ++kk) {                                     \
            short8 a;                                                        \
            a[0] = f2bf(RA_CUR[2 * kk][0]);                                  \
            a[1] = f2bf(RA_CUR[2 * kk][1]);                                  \
            a[2] = f2bf(RA_CUR[2 * kk][2]);                                  \
            a[3] = f2bf(RA_CUR[2 * kk][3]);                                  \
            a[4] = f2bf(RA_CUR[2 * kk + 1][0]);                              \
            a[5] = f2bf(RA_CUR[2 * kk + 1][1]);                              \
            a[6] = f2bf(RA_CUR[2 * kk + 1][2]);                              \
            a[7] = f2bf(RA_CUR[2 * kk + 1][3]);                              \
            _Pragma("unroll")                                                \
            for (int ni = 0; ni < 4; ++ni) {                                 \
                const short8* bp = (const short8*)                           \
                    &lds_b[RBUF][ni * 16 + ll][kk * 32 + lh * 8];            \
                acc[ni] = __builtin_amdgcn_mfma_f32_16x16x32_bf16(           \
                    a, *bp, acc[ni], 0, 0, 0);                               \
            }                                                                \
        }                                                                    \
        if ((T) + 1 < NT) {                                                  \
            _Pragma("unroll")                                                \
            for (int j = 0; j < 2; ++j) {                                    \
                short8 v;                                                    \
                _Pragma("unroll")                                            \
                for (int e = 0; e < 8; ++e) v[e] = f2bf(rn[8 * j + e]);      \
                *(short8*)&lds_b[(RBUF) ^ 1][sd][skb * 16 + 8 * j] = v;      \
            }                                                                \
        }                                                                    \
    }

    for (int t = 0; t < NT; t += 2) {
        ITER(t,     0, rA0, rA1);
        ITER(t + 1, 1, rA1, rA0);
    }
#undef ITER

    // ---- epilogue: C/D layout col = lane&15, row = (lane>>4)*4 + reg
    int r0 = m0 + w * 16 + lh * 4;
    float* ob = out + ((size_t)bh * S_DIM + r0) * D_DIM + ll;
#pragma unroll
    for (int ni = 0; ni < 4; ++ni) {
#pragma unroll
        for (int r = 0; r < 4; ++r)
            ob[(size_t)r * D_DIM + ni * 16] = acc[ni][r];
    }
}

extern "C" void kernel_launch(void* const* d_in, const int* in_sizes, int n_in,
                              void* d_out, int out_size, void* d_ws, size_t ws_size,
                              hipStream_t stream) {
    const float* x1 = (const float*)d_in[0];   // [2,16,2048,2048] softmax probs
    const float* x2 = (const float*)d_in[1];   // [2,16,2048,64]
    float* out = (float*)d_out;                // [2,16,2048,64]

    dim3 grid(1024);  // 32 bh * 32 M-tiles (BM=64)
    dim3 block(256);  // 4 waves
    hipLaunchKernelGGL(pv_gemm_kernel, grid, block, 0, stream, x1, x2, out);
}